// Round 1
// baseline (819.531 us; speedup 1.0000x reference)
//
#include <hip/hip_runtime.h>
#include <hip/hip_bf16.h>
#include <math.h>

#define BATCH 2
#define SEQ 2048
#define DMODEL 512
#define NH 8
#define DHEAD 64
#define NROWS (BATCH * SEQ)   // 4096

// out = x @ W + bias.  M=4096, N=K=512.
// scatter=1: write to (B,H,L,DH) head layout; scatter=0: row-major (M,N).
__global__ __launch_bounds__(256)
void gemm512(const float* __restrict__ x, const float* __restrict__ W,
             const float* __restrict__ bias, float* __restrict__ out, int scatter)
{
    __shared__ float As[16][65];
    __shared__ float Bs[16][65];
    const int tid = threadIdx.x;
    const int tx = tid & 15;
    const int ty = tid >> 4;
    const int m0 = blockIdx.y * 64;
    const int n0 = blockIdx.x * 64;
    float c[4][4] = {};

    for (int k0 = 0; k0 < DMODEL; k0 += 16) {
        {   // A tile 64x16 (one float4 per thread)
            const int m  = tid >> 2;
            const int k4 = (tid & 3) * 4;
            const float4 a = *reinterpret_cast<const float4*>(&x[(size_t)(m0 + m) * DMODEL + k0 + k4]);
            As[k4 + 0][m] = a.x; As[k4 + 1][m] = a.y; As[k4 + 2][m] = a.z; As[k4 + 3][m] = a.w;
        }
        {   // B tile 16x64
            const int kk = tid >> 4;
            const int n4 = (tid & 15) * 4;
            const float4 bv = *reinterpret_cast<const float4*>(&W[(size_t)(k0 + kk) * DMODEL + n0 + n4]);
            Bs[kk][n4 + 0] = bv.x; Bs[kk][n4 + 1] = bv.y; Bs[kk][n4 + 2] = bv.z; Bs[kk][n4 + 3] = bv.w;
        }
        __syncthreads();
        #pragma unroll
        for (int kk = 0; kk < 16; ++kk) {
            float a[4], b[4];
            #pragma unroll
            for (int i = 0; i < 4; ++i) a[i] = As[kk][ty * 4 + i];
            #pragma unroll
            for (int j = 0; j < 4; ++j) b[j] = Bs[kk][tx * 4 + j];
            #pragma unroll
            for (int i = 0; i < 4; ++i)
                #pragma unroll
                for (int j = 0; j < 4; ++j)
                    c[i][j] = fmaf(a[i], b[j], c[i][j]);
        }
        __syncthreads();
    }
    #pragma unroll
    for (int i = 0; i < 4; ++i) {
        const int rm = m0 + ty * 4 + i;
        const int bb = rm >> 11;            // / SEQ
        const int l  = rm & (SEQ - 1);
        #pragma unroll
        for (int j = 0; j < 4; ++j) {
            const int n = n0 + tx * 4 + j;
            const float v = c[i][j] + bias[n];
            if (scatter) {
                const int h = n >> 6, dh = n & 63;
                out[(((size_t)bb * NH + h) * SEQ + l) * DHEAD + dh] = v;
            } else {
                out[(size_t)rm * DMODEL + n] = v;
            }
        }
    }
}

// Causal relative attention.  One workgroup handles query blocks {31-pair, pair}
// for head bh -> exactly 33 key-tiles of work each (load balanced).
// Phase 1: raw S=(QK^T + Q.E_rel)/8 -> d_out attn region (scratch) + rowmax
// Phase 2: re-read S, p=exp(S-max), rowsum, O += p @ V
// Phase 3: re-read S, write p/rowsum (zeros beyond the diagonal)
__global__ __launch_bounds__(256)
void attn_kernel(const float* __restrict__ qws, const float* __restrict__ kws,
                 const float* __restrict__ vws, const float* __restrict__ E,
                 float* __restrict__ attnw, float* __restrict__ ows)
{
    __shared__ float Qs[64][65];
    __shared__ float Ks[64][65];     // K in phase 1, V in phase 2
    __shared__ float Es[127][65];
    __shared__ float Ss[64][65];
    __shared__ float red[64][17];
    __shared__ float rowmax[64];
    __shared__ float rowsum[64];

    const int tid = threadIdx.x;
    const int tx = tid & 15;
    const int ty = tid >> 4;
    const int bh   = blockIdx.x >> 4;
    const int pair = blockIdx.x & 15;
    const int b = bh >> 3;
    const int h = bh & 7;

    const float* qbase = qws + (size_t)bh * SEQ * DHEAD;
    const float* kbase = kws + (size_t)bh * SEQ * DHEAD;
    const float* vbase = vws + (size_t)bh * SEQ * DHEAD;
    float* abase = attnw + (size_t)bh * SEQ * SEQ;

    for (int rep = 0; rep < 2; ++rep) {
        const int iblk = (rep == 0) ? (31 - pair) : pair;   // heavy block first
        const int i0 = iblk * 64;
        __syncthreads();
        if (tid < 64) { rowmax[tid] = -3.0e38f; rowsum[tid] = 0.0f; }
        for (int t = tid; t < 64 * 16; t += 256) {
            const int m = t >> 4, c4 = (t & 15) * 4;
            const float4 v4 = *reinterpret_cast<const float4*>(&qbase[(size_t)(i0 + m) * DHEAD + c4]);
            Qs[m][c4 + 0] = v4.x; Qs[m][c4 + 1] = v4.y; Qs[m][c4 + 2] = v4.z; Qs[m][c4 + 3] = v4.w;
        }
        __syncthreads();

        // ---------------- Phase 1 ----------------
        for (int j0 = 0; j0 <= i0; j0 += 64) {
            for (int t = tid; t < 64 * 16; t += 256) {
                const int m = t >> 4, c4 = (t & 15) * 4;
                const float4 v4 = *reinterpret_cast<const float4*>(&kbase[(size_t)(j0 + m) * DHEAD + c4]);
                Ks[m][c4 + 0] = v4.x; Ks[m][c4 + 1] = v4.y; Ks[m][c4 + 2] = v4.z; Ks[m][c4 + 3] = v4.w;
            }
            const int rbase = SEQ - 64 - i0 + j0;   // E row window base; rr = 63 - i + j
            for (int t = tid; t < 127 * 16; t += 256) {
                const int rr = t >> 4, c4 = (t & 15) * 4;
                const int r = rbase + rr;
                if (r >= 0 && r < SEQ) {
                    const float4 v4 = *reinterpret_cast<const float4*>(&E[(size_t)r * DHEAD + c4]);
                    Es[rr][c4 + 0] = v4.x; Es[rr][c4 + 1] = v4.y; Es[rr][c4 + 2] = v4.z; Es[rr][c4 + 3] = v4.w;
                } else {
                    Es[rr][c4 + 0] = 0.f; Es[rr][c4 + 1] = 0.f; Es[rr][c4 + 2] = 0.f; Es[rr][c4 + 3] = 0.f;
                }
            }
            __syncthreads();

            float accK[4][4] = {};
            float accE[4][4] = {};
            const int rb = 63 + 4 * (tx - ty);   // rr = rb + (jj - ii), rb in [3,123]
            for (int d = 0; d < 64; ++d) {
                float qv[4], kv[4], ev[7];
                #pragma unroll
                for (int i = 0; i < 4; ++i) qv[i] = Qs[ty * 4 + i][d];
                #pragma unroll
                for (int j = 0; j < 4; ++j) kv[j] = Ks[tx * 4 + j][d];
                #pragma unroll
                for (int t = 0; t < 7; ++t) ev[t] = Es[rb - 3 + t][d];
                #pragma unroll
                for (int i = 0; i < 4; ++i)
                    #pragma unroll
                    for (int j = 0; j < 4; ++j) {
                        accK[i][j] = fmaf(qv[i], kv[j], accK[i][j]);
                        accE[i][j] = fmaf(qv[i], ev[3 + j - i], accE[i][j]);
                    }
            }
            #pragma unroll
            for (int i = 0; i < 4; ++i) {
                const int gi = i0 + ty * 4 + i;
                #pragma unroll
                for (int j = 0; j < 4; ++j) {
                    const int gj = j0 + tx * 4 + j;
                    float sv = (accK[i][j] + accE[i][j]) * 0.125f;
                    if (gj > gi) sv = -1.0e30f;
                    Ss[ty * 4 + i][tx * 4 + j] = sv;
                }
            }
            __syncthreads();
            for (int t = tid; t < 64 * 16; t += 256) {
                const int m = t >> 4, c4 = (t & 15) * 4;
                const float4 v4 = make_float4(Ss[m][c4], Ss[m][c4 + 1], Ss[m][c4 + 2], Ss[m][c4 + 3]);
                *reinterpret_cast<float4*>(&abase[(size_t)(i0 + m) * SEQ + j0 + c4]) = v4;
            }
            if (tid < 64) {
                float mx = rowmax[tid];
                #pragma unroll 8
                for (int j = 0; j < 64; ++j) mx = fmaxf(mx, Ss[tid][j]);
                rowmax[tid] = mx;
            }
            __syncthreads();
        }

        // ---------------- Phase 2 ----------------
        float o[4][4] = {};
        for (int j0 = 0; j0 <= i0; j0 += 64) {
            for (int t = tid; t < 64 * 16; t += 256) {
                const int m = t >> 4, c4 = (t & 15) * 4;
                const float4 v4 = *reinterpret_cast<const float4*>(&vbase[(size_t)(j0 + m) * DHEAD + c4]);
                Ks[m][c4 + 0] = v4.x; Ks[m][c4 + 1] = v4.y; Ks[m][c4 + 2] = v4.z; Ks[m][c4 + 3] = v4.w;
            }
            #pragma unroll
            for (int i = 0; i < 4; ++i) {
                const int li = ty * 4 + i;
                const float4 sv = *reinterpret_cast<const float4*>(&abase[(size_t)(i0 + li) * SEQ + j0 + tx * 4]);
                const float m = rowmax[li];
                const float p0 = __expf(sv.x - m);
                const float p1 = __expf(sv.y - m);
                const float p2 = __expf(sv.z - m);
                const float p3 = __expf(sv.w - m);
                Ss[li][tx * 4 + 0] = p0; Ss[li][tx * 4 + 1] = p1;
                Ss[li][tx * 4 + 2] = p2; Ss[li][tx * 4 + 3] = p3;
                red[li][tx] = p0 + p1 + p2 + p3;
            }
            __syncthreads();
            if (tid < 64) {
                float s = rowsum[tid];
                #pragma unroll
                for (int t = 0; t < 16; ++t) s += red[tid][t];
                rowsum[tid] = s;
            }
            for (int k = 0; k < 64; ++k) {
                float pv[4], vv[4];
                #pragma unroll
                for (int i = 0; i < 4; ++i) pv[i] = Ss[ty * 4 + i][k];
                #pragma unroll
                for (int j = 0; j < 4; ++j) vv[j] = Ks[k][tx * 4 + j];
                #pragma unroll
                for (int i = 0; i < 4; ++i)
                    #pragma unroll
                    for (int j = 0; j < 4; ++j)
                        o[i][j] = fmaf(pv[i], vv[j], o[i][j]);
            }
            __syncthreads();
        }

        // finalize O -> ows in (B, L, D) layout (col = h*64 + d)
        #pragma unroll
        for (int i = 0; i < 4; ++i) {
            const float iv = 1.0f / rowsum[ty * 4 + i];
            float4 ov;
            ov.x = o[i][0] * iv; ov.y = o[i][1] * iv;
            ov.z = o[i][2] * iv; ov.w = o[i][3] * iv;
            const int gl = i0 + ty * 4 + i;
            *reinterpret_cast<float4*>(&ows[((size_t)b * SEQ + gl) * DMODEL + h * DHEAD + tx * 4]) = ov;
        }

        // ---------------- Phase 3: final normalized weights ----------------
        for (int j0 = 0; j0 < SEQ; j0 += 64) {
            if (j0 <= i0) {
                #pragma unroll
                for (int i = 0; i < 4; ++i) {
                    const int li = ty * 4 + i;
                    const float m  = rowmax[li];
                    const float iv = 1.0f / rowsum[li];
                    float4 sv = *reinterpret_cast<const float4*>(&abase[(size_t)(i0 + li) * SEQ + j0 + tx * 4]);
                    sv.x = __expf(sv.x - m) * iv;
                    sv.y = __expf(sv.y - m) * iv;
                    sv.z = __expf(sv.z - m) * iv;
                    sv.w = __expf(sv.w - m) * iv;
                    *reinterpret_cast<float4*>(&abase[(size_t)(i0 + li) * SEQ + j0 + tx * 4]) = sv;
                }
            } else {
                const float4 z = make_float4(0.f, 0.f, 0.f, 0.f);
                #pragma unroll
                for (int i = 0; i < 4; ++i) {
                    const int li = ty * 4 + i;
                    *reinterpret_cast<float4*>(&abase[(size_t)(i0 + li) * SEQ + j0 + tx * 4]) = z;
                }
            }
        }
    }
}

extern "C" void kernel_launch(void* const* d_in, const int* in_sizes, int n_in,
                              void* d_out, int out_size, void* d_ws, size_t ws_size,
                              hipStream_t stream) {
    const float* q_in = (const float*)d_in[0];
    const float* k_in = (const float*)d_in[1];
    const float* v_in = (const float*)d_in[2];
    // d_in[3] = mask (implicit causal; unused)
    const float* Wq  = (const float*)d_in[4];
    const float* bq  = (const float*)d_in[5];
    const float* Wk  = (const float*)d_in[6];
    const float* bk  = (const float*)d_in[7];
    const float* Wv  = (const float*)d_in[8];
    const float* bv  = (const float*)d_in[9];
    const float* Wfc = (const float*)d_in[10];
    const float* bfc = (const float*)d_in[11];
    const float* E   = (const float*)d_in[12];

    float* out0  = (float*)d_out;                       // (B, L, D)
    float* attnw = out0 + (size_t)BATCH * SEQ * DMODEL; // (B, H, L, L)

    float* qws = (float*)d_ws;                          // (B,H,L,DH)
    float* kws = qws + (size_t)BATCH * SEQ * DMODEL;
    float* vws = kws + (size_t)BATCH * SEQ * DMODEL;
    float* ows = vws + (size_t)BATCH * SEQ * DMODEL;    // (B, L, D)

    dim3 gg(DMODEL / 64, NROWS / 64);
    gemm512<<<gg, 256, 0, stream>>>(q_in, Wq, bq, qws, 1);
    gemm512<<<gg, 256, 0, stream>>>(k_in, Wk, bk, kws, 1);
    gemm512<<<gg, 256, 0, stream>>>(v_in, Wv, bv, vws, 1);
    attn_kernel<<<dim3(256), 256, 0, stream>>>(qws, kws, vws, E, attnw, ows);
    gemm512<<<gg, 256, 0, stream>>>(ows, Wfc, bfc, out0, 0);
}

// Round 2
// 375.251 us; speedup vs baseline: 2.1840x; 2.1840x over previous
//
#include <hip/hip_runtime.h>
#include <math.h>

#define L 2048
#define DMODEL 512
#define NH 8
#define DH 64
#define NROWS 4096   // B*L

typedef __attribute__((ext_vector_type(4))) float f32x4;
typedef __attribute__((ext_vector_type(8))) short s16x8;

#define MFMA(a, b, c) __builtin_amdgcn_mfma_f32_16x16x32_bf16(a, b, c, 0, 0, 0)

static __device__ __forceinline__ ushort f2b(float f) {
    union { float f; unsigned u; } v; v.f = f;
    unsigned r = v.u + 0x7FFF + ((v.u >> 16) & 1);
    return (ushort)(r >> 16);
}
static __device__ __forceinline__ float b2f(ushort u) {
    union { unsigned u; float f; } v; v.u = ((unsigned)u) << 16;
    return v.f;
}

// ---------- f32 -> bf16 convert (8 elems/thread) ----------
__global__ __launch_bounds__(256)
void cvt_bf16(const float* __restrict__ in, ushort* __restrict__ out, int n8) {
    int i = blockIdx.x * 256 + threadIdx.x;
    if (i < n8) {
        float4 a = *reinterpret_cast<const float4*>(&in[(size_t)i * 8]);
        float4 b = *reinterpret_cast<const float4*>(&in[(size_t)i * 8 + 4]);
        ushort4 o0; o0.x = f2b(a.x); o0.y = f2b(a.y); o0.z = f2b(a.z); o0.w = f2b(a.w);
        ushort4 o1; o1.x = f2b(b.x); o1.y = f2b(b.y); o1.z = f2b(b.z); o1.w = f2b(b.w);
        *reinterpret_cast<ushort4*>(&out[(size_t)i * 8]) = o0;
        *reinterpret_cast<ushort4*>(&out[(size_t)i * 8 + 4]) = o1;
    }
}

// ---------- W (512x512 f32, row-major [k][n]) -> Wt bf16 [n][k] ----------
__global__ __launch_bounds__(256)
void transpose_w(const float* __restrict__ W0, const float* __restrict__ W1,
                 const float* __restrict__ W2, const float* __restrict__ W3,
                 ushort* __restrict__ T0, ushort* __restrict__ T1,
                 ushort* __restrict__ T2, ushort* __restrict__ T3) {
    const int z = blockIdx.z;
    const float* W = z == 0 ? W0 : (z == 1 ? W1 : (z == 2 ? W2 : W3));
    ushort* T = z == 0 ? T0 : (z == 1 ? T1 : (z == 2 ? T2 : T3));
    __shared__ float Ls[64][65];
    const int tid = threadIdx.x;
    const int k0 = blockIdx.y * 64, n0 = blockIdx.x * 64;
    #pragma unroll
    for (int i = 0; i < 4; ++i) {
        int kk = (tid >> 4) + i * 16, n4 = (tid & 15) * 4;
        float4 v = *reinterpret_cast<const float4*>(&W[(size_t)(k0 + kk) * 512 + n0 + n4]);
        Ls[kk][n4] = v.x; Ls[kk][n4 + 1] = v.y; Ls[kk][n4 + 2] = v.z; Ls[kk][n4 + 3] = v.w;
    }
    __syncthreads();
    #pragma unroll
    for (int i = 0; i < 4; ++i) {
        int nn = (tid >> 4) + i * 16, k4 = (tid & 15) * 4;
        ushort4 o;
        o.x = f2b(Ls[k4 + 0][nn]); o.y = f2b(Ls[k4 + 1][nn]);
        o.z = f2b(Ls[k4 + 2][nn]); o.w = f2b(Ls[k4 + 3][nn]);
        *reinterpret_cast<ushort4*>(&T[(size_t)(n0 + nn) * 512 + k0 + k4]) = o;
    }
}

// ---------- bf16 MFMA GEMM: out = A(4096x512) @ Wt^T + bias ----------
// mode 0: f32 row-major out. mode 1: bf16 scatter to (B,H,L,DH).
__global__ __launch_bounds__(256)
void gemm_bf16(const ushort* __restrict__ A0, const ushort* __restrict__ A1,
               const ushort* __restrict__ A2,
               const ushort* __restrict__ W0, const ushort* __restrict__ W1,
               const ushort* __restrict__ W2,
               const float* __restrict__ b0, const float* __restrict__ b1,
               const float* __restrict__ b2,
               void* o0, void* o1, void* o2, int mode) {
    const int z = blockIdx.z;
    const ushort* A  = z == 0 ? A0 : (z == 1 ? A1 : A2);
    const ushort* Wt = z == 0 ? W0 : (z == 1 ? W1 : W2);
    const float* bias = z == 0 ? b0 : (z == 1 ? b1 : b2);
    void* outp = z == 0 ? o0 : (z == 1 ? o1 : o2);

    __shared__ ushort As[128][40];
    __shared__ ushort Bs[64][40];
    const int tid = threadIdx.x;
    const int w = tid >> 6, lane = tid & 63, g = lane >> 4, c = lane & 15;
    const int m0 = blockIdx.y * 128, n0 = blockIdx.x * 64;

    f32x4 acc[2][4];
    #pragma unroll
    for (int rs = 0; rs < 2; ++rs)
        #pragma unroll
        for (int cs = 0; cs < 4; ++cs) acc[rs][cs] = (f32x4){0.f, 0.f, 0.f, 0.f};

    float bsv[4];
    #pragma unroll
    for (int cs = 0; cs < 4; ++cs) bsv[cs] = bias[n0 + 16 * cs + c];

    for (int k0 = 0; k0 < 512; k0 += 32) {
        {
            int row = tid >> 1, kh = (tid & 1) * 16;
            const ushort* p = A + (size_t)(m0 + row) * 512 + k0 + kh;
            uint4 x0 = *reinterpret_cast<const uint4*>(p);
            uint4 x1 = *reinterpret_cast<const uint4*>(p + 8);
            *reinterpret_cast<uint4*>(&As[row][kh]) = x0;
            *reinterpret_cast<uint4*>(&As[row][kh + 8]) = x1;
        }
        {
            int n = tid >> 2, kh = (tid & 3) * 8;
            uint4 x = *reinterpret_cast<const uint4*>(&Wt[(size_t)(n0 + n) * 512 + k0 + kh]);
            *reinterpret_cast<uint4*>(&Bs[n][kh]) = x;
        }
        __syncthreads();
        s16x8 af[2], bf[4];
        #pragma unroll
        for (int rs = 0; rs < 2; ++rs)
            af[rs] = *reinterpret_cast<const s16x8*>(&As[32 * w + 16 * rs + c][8 * g]);
        #pragma unroll
        for (int cs = 0; cs < 4; ++cs)
            bf[cs] = *reinterpret_cast<const s16x8*>(&Bs[16 * cs + c][8 * g]);
        #pragma unroll
        for (int rs = 0; rs < 2; ++rs)
            #pragma unroll
            for (int cs = 0; cs < 4; ++cs)
                acc[rs][cs] = MFMA(af[rs], bf[cs], acc[rs][cs]);
        __syncthreads();
    }
    #pragma unroll
    for (int rs = 0; rs < 2; ++rs)
        #pragma unroll
        for (int cs = 0; cs < 4; ++cs)
            #pragma unroll
            for (int r = 0; r < 4; ++r) {
                int row = m0 + 32 * w + 16 * rs + 4 * g + r;
                int n = n0 + 16 * cs + c;
                float v = acc[rs][cs][r] + bsv[cs];
                if (mode == 0) {
                    ((float*)outp)[(size_t)row * 512 + n] = v;
                } else {
                    int bb = row >> 11, l = row & 2047, hh = n >> 6, dh = n & 63;
                    ((ushort*)outp)[(((size_t)bb * NH + hh) * L + l) * DH + dh] = f2b(v);
                }
            }
}

// ---------- fused relative attention ----------
// wg = (bh, pair): processes i-blocks {pair, 63-pair} of 32 query rows each.
__global__ __launch_bounds__(256)
void attn(const ushort* __restrict__ qws, const ushort* __restrict__ kws,
          const ushort* __restrict__ vws, const ushort* __restrict__ Ebf,
          float* __restrict__ attnw, ushort* __restrict__ ows) {
    __shared__ ushort Pst[32][2056];
    __shared__ ushort Vt[64][72];
    __shared__ float Tst[32][100];
    __shared__ float mtile[32][32];
    __shared__ float mrow[32], lrow[32], scalef[32];
    __shared__ float redm[4][32], reds[4][32];

    const int tid = threadIdx.x;
    const int w = tid >> 6, lane = tid & 63, g = lane >> 4, c = lane & 15;
    const int bh = blockIdx.x >> 5, pr = blockIdx.x & 31;
    const int b = bh >> 3, h = bh & 7;
    const ushort* qb = qws + (size_t)bh * L * DH;
    const ushort* kb = kws + (size_t)bh * L * DH;
    const ushort* vb = vws + (size_t)bh * L * DH;
    float* ab = attnw + (size_t)bh * L * L;

    for (int rep = 0; rep < 2; ++rep) {
        const int ib = rep ? (63 - pr) : pr;
        const int i0 = ib * 32;
        const int nj = (ib >> 1) + 1;
        __syncthreads();                 // LDS reuse across reps
        if (tid < 32) { mrow[tid] = -1e30f; lrow[tid] = 0.f; }
        f32x4 O0 = {0.f, 0.f, 0.f, 0.f}, O1 = {0.f, 0.f, 0.f, 0.f};
        s16x8 aq[2][2];
        #pragma unroll
        for (int rs = 0; rs < 2; ++rs)
            #pragma unroll
            for (int ks = 0; ks < 2; ++ks)
                aq[rs][ks] = *reinterpret_cast<const s16x8*>(
                    qb + (size_t)(i0 + 16 * rs + c) * DH + 32 * ks + 8 * g);

        for (int tj = 0; tj < nj; ++tj) {
            const int j0 = tj * 64;
            // V tile -> regs (LDS write deferred past barrier A)
            uint4 v0, v1;
            {
                const int jj = tid >> 2, d8 = (tid & 3) * 16;
                const ushort* vp = vb + (size_t)(j0 + jj) * DH + d8;
                v0 = *reinterpret_cast<const uint4*>(vp);
                v1 = *reinterpret_cast<const uint4*>(vp + 8);
            }
            // T = Q . E_win^T  (strip 32 x 96)
            const int rbase = L - 32 - i0 + j0;
            const int ncts = (w < 2) ? 2 : 1;
            f32x4 TT[2][2];
            for (int cti = 0; cti < ncts; ++cti) {
                int ct = w + cti * 4;
                s16x8 be[2];
                #pragma unroll
                for (int ks = 0; ks < 2; ++ks) {
                    int rg = rbase + 16 * ct + c;
                    rg = rg < 0 ? 0 : (rg > L - 1 ? L - 1 : rg);
                    be[ks] = *reinterpret_cast<const s16x8*>(
                        Ebf + (size_t)rg * DH + 32 * ks + 8 * g);
                }
                #pragma unroll
                for (int rs = 0; rs < 2; ++rs) {
                    f32x4 t = {0.f, 0.f, 0.f, 0.f};
                    t = MFMA(aq[rs][0], be[0], t);
                    t = MFMA(aq[rs][1], be[1], t);
                    TT[cti][rs] = t;
                }
            }
            // QK^T
            f32x4 SK[2];
            {
                s16x8 bk[2];
                #pragma unroll
                for (int ks = 0; ks < 2; ++ks)
                    bk[ks] = *reinterpret_cast<const s16x8*>(
                        kb + (size_t)(j0 + 16 * w + c) * DH + 32 * ks + 8 * g);
                #pragma unroll
                for (int rs = 0; rs < 2; ++rs) {
                    f32x4 t = {0.f, 0.f, 0.f, 0.f};
                    t = MFMA(aq[rs][0], bk[0], t);
                    t = MFMA(aq[rs][1], bk[1], t);
                    SK[rs] = t;
                }
            }
            __syncthreads();             // A: previous tile's LDS consumers done
            for (int cti = 0; cti < ncts; ++cti) {
                int ct = w + cti * 4;
                #pragma unroll
                for (int rs = 0; rs < 2; ++rs)
                    #pragma unroll
                    for (int r = 0; r < 4; ++r)
                        Tst[16 * rs + 4 * g + r][16 * ct + c] = TT[cti][rs][r];
            }
            {
                const int jj = tid >> 2, d8 = (tid & 3) * 16;
                const ushort* pv = (const ushort*)&v0;
                #pragma unroll
                for (int e = 0; e < 8; ++e) Vt[d8 + e][jj] = pv[e];
                pv = (const ushort*)&v1;
                #pragma unroll
                for (int e = 0; e < 8; ++e) Vt[d8 + 8 + e][jj] = pv[e];
            }
            __syncthreads();             // B: Tst, Vt visible
            float sv[2][4];
            #pragma unroll
            for (int rs = 0; rs < 2; ++rs)
                #pragma unroll
                for (int r = 0; r < 4; ++r) {
                    int il = 16 * rs + 4 * g + r;
                    int jl = 16 * w + c;
                    int rr = 31 + jl - il;
                    float s = (SK[rs][r] + Tst[il][rr]) * 0.125f;
                    sv[rs][r] = (j0 + jl <= i0 + il) ? s : -1e30f;
                }
            #pragma unroll
            for (int rs = 0; rs < 2; ++rs)
                #pragma unroll
                for (int r = 0; r < 4; ++r) {
                    float m = sv[rs][r];
                    for (int d = 1; d < 16; d <<= 1) m = fmaxf(m, __shfl_xor(m, d, 64));
                    if (c == 0) redm[w][16 * rs + 4 * g + r] = m;
                }
            __syncthreads();             // C: redm ready
            if (tid < 32) {
                float m = mrow[tid];
                float mn = fmaxf(fmaxf(redm[0][tid], redm[1][tid]),
                                 fmaxf(redm[2][tid], redm[3][tid]));
                mn = fmaxf(mn, m);
                float sc = __expf(m - mn);
                mrow[tid] = mn; scalef[tid] = sc; lrow[tid] *= sc; mtile[tid][tj] = mn;
            }
            __syncthreads();             // D: mrow/scalef ready
            float psum[2][4];
            #pragma unroll
            for (int rs = 0; rs < 2; ++rs)
                #pragma unroll
                for (int r = 0; r < 4; ++r) {
                    int il = 16 * rs + 4 * g + r;
                    float p = __expf(sv[rs][r] - mrow[il]);
                    Pst[il][j0 + 16 * w + c] = f2b(p);
                    psum[rs][r] = p;
                }
            #pragma unroll
            for (int rs = 0; rs < 2; ++rs)
                #pragma unroll
                for (int r = 0; r < 4; ++r) {
                    float s = psum[rs][r];
                    for (int d = 1; d < 16; d <<= 1) s += __shfl_xor(s, d, 64);
                    if (c == 0) reds[w][16 * rs + 4 * g + r] = s;
                }
            #pragma unroll
            for (int r = 0; r < 4; ++r) {
                O0[r] *= scalef[4 * g + r];
                O1[r] *= scalef[16 + 4 * g + r];
            }
            __syncthreads();             // E: Pst, reds ready
            if (tid < 32)
                lrow[tid] += reds[0][tid] + reds[1][tid] + reds[2][tid] + reds[3][tid];
            #pragma unroll
            for (int ks = 0; ks < 2; ++ks) {
                s16x8 bv = *reinterpret_cast<const s16x8*>(&Vt[16 * w + c][32 * ks + 8 * g]);
                s16x8 pa0 = *reinterpret_cast<const s16x8*>(&Pst[c][j0 + 32 * ks + 8 * g]);
                s16x8 pa1 = *reinterpret_cast<const s16x8*>(&Pst[16 + c][j0 + 32 * ks + 8 * g]);
                O0 = MFMA(pa0, bv, O0);
                O1 = MFMA(pa1, bv, O1);
            }
        } // tj
        __syncthreads();
        if (tid < 32) scalef[tid] = 1.0f / lrow[tid];
        __syncthreads();
        // O -> ows (bf16, (B,L,D) layout)
        #pragma unroll
        for (int rs = 0; rs < 2; ++rs) {
            #pragma unroll
            for (int r = 0; r < 4; ++r) {
                int il = 16 * rs + 4 * g + r;
                float v = (rs ? O1[r] : O0[r]) * scalef[il];
                ows[((size_t)b * L + i0 + il) * DMODEL + h * DH + 16 * w + c] = f2b(v);
            }
        }
        // final normalized attention weights (full 2048 cols incl. zeros)
        for (int it = 0; it < 64; ++it) {
            int row = tid >> 3;
            int col = it * 32 + (tid & 7) * 4;
            int ig = i0 + row;
            float f = __expf(mtile[row][col >> 6] - mrow[row]) * scalef[row];
            ushort4 pb = *reinterpret_cast<const ushort4*>(&Pst[row][col]);
            float4 o;
            o.x = (col + 0 <= ig) ? b2f(pb.x) * f : 0.f;
            o.y = (col + 1 <= ig) ? b2f(pb.y) * f : 0.f;
            o.z = (col + 2 <= ig) ? b2f(pb.z) * f : 0.f;
            o.w = (col + 3 <= ig) ? b2f(pb.w) * f : 0.f;
            *reinterpret_cast<float4*>(&ab[(size_t)ig * L + col]) = o;
        }
    } // rep
}

extern "C" void kernel_launch(void* const* d_in, const int* in_sizes, int n_in,
                              void* d_out, int out_size, void* d_ws, size_t ws_size,
                              hipStream_t stream) {
    const float* q_in = (const float*)d_in[0];
    const float* k_in = (const float*)d_in[1];
    const float* v_in = (const float*)d_in[2];
    const float* Wq  = (const float*)d_in[4];
    const float* bq  = (const float*)d_in[5];
    const float* Wk  = (const float*)d_in[6];
    const float* bk  = (const float*)d_in[7];
    const float* Wv  = (const float*)d_in[8];
    const float* bv  = (const float*)d_in[9];
    const float* Wfc = (const float*)d_in[10];
    const float* bfc = (const float*)d_in[11];
    const float* E   = (const float*)d_in[12];

    float* out0  = (float*)d_out;                        // (B,L,D) f32
    float* attnw = out0 + (size_t)2 * L * DMODEL;        // (B,H,L,L) f32

    const size_t NA = (size_t)NROWS * DMODEL;            // 2,097,152
    ushort* ws = (ushort*)d_ws;
    ushort* qx   = ws;
    ushort* kx   = qx + NA;
    ushort* vx   = kx + NA;
    ushort* Ebf  = vx + NA;                              // 131072
    ushort* Wqt  = Ebf + (size_t)L * DH;
    ushort* Wkt  = Wqt + 262144;
    ushort* Wvt  = Wkt + 262144;
    ushort* Wfct = Wvt + 262144;
    ushort* qws  = Wfct + 262144;
    ushort* kws  = qws + NA;
    ushort* vws  = kws + NA;
    ushort* ows  = vws + NA;

    cvt_bf16<<<dim3(1024), 256, 0, stream>>>(q_in, qx, (int)(NA / 8));
    cvt_bf16<<<dim3(1024), 256, 0, stream>>>(k_in, kx, (int)(NA / 8));
    cvt_bf16<<<dim3(1024), 256, 0, stream>>>(v_in, vx, (int)(NA / 8));
    cvt_bf16<<<dim3(64), 256, 0, stream>>>(E, Ebf, (int)(L * DH / 8));
    transpose_w<<<dim3(8, 8, 4), 256, 0, stream>>>(Wq, Wk, Wv, Wfc, Wqt, Wkt, Wvt, Wfct);
    gemm_bf16<<<dim3(8, 32, 3), 256, 0, stream>>>(qx, kx, vx, Wqt, Wkt, Wvt,
                                                  bq, bk, bv, qws, kws, vws, 1);
    attn<<<dim3(512), 256, 0, stream>>>(qws, kws, vws, Ebf, attnw, ows);
    gemm_bf16<<<dim3(8, 32, 1), 256, 0, stream>>>(ows, ows, ows, Wfct, Wfct, Wfct,
                                                  bfc, bfc, bfc, out0, out0, out0, 0);
}

// Round 3
// 284.979 us; speedup vs baseline: 2.8758x; 1.3168x over previous
//
#include <hip/hip_runtime.h>
#include <math.h>

#define L 2048
#define DMODEL 512
#define NH 8
#define DH 64
#define NROWS 4096   // B*L

typedef __attribute__((ext_vector_type(4))) float f32x4;
typedef __attribute__((ext_vector_type(8))) short s16x8;

#define MFMA(a, b, c) __builtin_amdgcn_mfma_f32_16x16x32_bf16(a, b, c, 0, 0, 0)

static __device__ __forceinline__ ushort f2b(float f) {
    union { float f; unsigned u; } v; v.f = f;
    unsigned r = v.u + 0x7FFF + ((v.u >> 16) & 1);
    return (ushort)(r >> 16);
}
static __device__ __forceinline__ float b2f(ushort u) {
    union { unsigned u; float f; } v; v.u = ((unsigned)u) << 16;
    return v.f;
}

// ---------- f32 -> bf16 convert (8 elems/thread) ----------
__global__ __launch_bounds__(256)
void cvt_bf16(const float* __restrict__ in, ushort* __restrict__ out, int n8) {
    int i = blockIdx.x * 256 + threadIdx.x;
    if (i < n8) {
        float4 a = *reinterpret_cast<const float4*>(&in[(size_t)i * 8]);
        float4 b = *reinterpret_cast<const float4*>(&in[(size_t)i * 8 + 4]);
        ushort4 o0; o0.x = f2b(a.x); o0.y = f2b(a.y); o0.z = f2b(a.z); o0.w = f2b(a.w);
        ushort4 o1; o1.x = f2b(b.x); o1.y = f2b(b.y); o1.z = f2b(b.z); o1.w = f2b(b.w);
        *reinterpret_cast<ushort4*>(&out[(size_t)i * 8]) = o0;
        *reinterpret_cast<ushort4*>(&out[(size_t)i * 8 + 4]) = o1;
    }
}

// ---------- W (512x512 f32, row-major [k][n]) -> Wt bf16 [n][k] ----------
__global__ __launch_bounds__(256)
void transpose_w(const float* __restrict__ W0, const float* __restrict__ W1,
                 const float* __restrict__ W2, const float* __restrict__ W3,
                 ushort* __restrict__ T0, ushort* __restrict__ T1,
                 ushort* __restrict__ T2, ushort* __restrict__ T3) {
    const int z = blockIdx.z;
    const float* W = z == 0 ? W0 : (z == 1 ? W1 : (z == 2 ? W2 : W3));
    ushort* T = z == 0 ? T0 : (z == 1 ? T1 : (z == 2 ? T2 : T3));
    __shared__ float Ls[64][65];
    const int tid = threadIdx.x;
    const int k0 = blockIdx.y * 64, n0 = blockIdx.x * 64;
    #pragma unroll
    for (int i = 0; i < 4; ++i) {
        int kk = (tid >> 4) + i * 16, n4 = (tid & 15) * 4;
        float4 v = *reinterpret_cast<const float4*>(&W[(size_t)(k0 + kk) * 512 + n0 + n4]);
        Ls[kk][n4] = v.x; Ls[kk][n4 + 1] = v.y; Ls[kk][n4 + 2] = v.z; Ls[kk][n4 + 3] = v.w;
    }
    __syncthreads();
    #pragma unroll
    for (int i = 0; i < 4; ++i) {
        int nn = (tid >> 4) + i * 16, k4 = (tid & 15) * 4;
        ushort4 o;
        o.x = f2b(Ls[k4 + 0][nn]); o.y = f2b(Ls[k4 + 1][nn]);
        o.z = f2b(Ls[k4 + 2][nn]); o.w = f2b(Ls[k4 + 3][nn]);
        *reinterpret_cast<ushort4*>(&T[(size_t)(n0 + nn) * 512 + k0 + k4]) = o;
    }
}

// ---------- bf16 MFMA GEMM: out = A(4096x512) @ Wt^T + bias ----------
__global__ __launch_bounds__(256)
void gemm_bf16(const ushort* __restrict__ A0, const ushort* __restrict__ A1,
               const ushort* __restrict__ A2,
               const ushort* __restrict__ W0, const ushort* __restrict__ W1,
               const ushort* __restrict__ W2,
               const float* __restrict__ b0, const float* __restrict__ b1,
               const float* __restrict__ b2,
               void* o0, void* o1, void* o2, int mode) {
    const int z = blockIdx.z;
    const ushort* A  = z == 0 ? A0 : (z == 1 ? A1 : A2);
    const ushort* Wt = z == 0 ? W0 : (z == 1 ? W1 : W2);
    const float* bias = z == 0 ? b0 : (z == 1 ? b1 : b2);
    void* outp = z == 0 ? o0 : (z == 1 ? o1 : o2);

    __shared__ ushort As[128][40];
    __shared__ ushort Bs[64][40];
    const int tid = threadIdx.x;
    const int w = tid >> 6, lane = tid & 63, g = lane >> 4, c = lane & 15;
    const int m0 = blockIdx.y * 128, n0 = blockIdx.x * 64;

    f32x4 acc[2][4];
    #pragma unroll
    for (int rs = 0; rs < 2; ++rs)
        #pragma unroll
        for (int cs = 0; cs < 4; ++cs) acc[rs][cs] = (f32x4){0.f, 0.f, 0.f, 0.f};

    float bsv[4];
    #pragma unroll
    for (int cs = 0; cs < 4; ++cs) bsv[cs] = bias[n0 + 16 * cs + c];

    for (int k0 = 0; k0 < 512; k0 += 32) {
        {
            int row = tid >> 1, kh = (tid & 1) * 16;
            const ushort* p = A + (size_t)(m0 + row) * 512 + k0 + kh;
            uint4 x0 = *reinterpret_cast<const uint4*>(p);
            uint4 x1 = *reinterpret_cast<const uint4*>(p + 8);
            *reinterpret_cast<uint4*>(&As[row][kh]) = x0;
            *reinterpret_cast<uint4*>(&As[row][kh + 8]) = x1;
        }
        {
            int n = tid >> 2, kh = (tid & 3) * 8;
            uint4 x = *reinterpret_cast<const uint4*>(&Wt[(size_t)(n0 + n) * 512 + k0 + kh]);
            *reinterpret_cast<uint4*>(&Bs[n][kh]) = x;
        }
        __syncthreads();
        s16x8 af[2], bf[4];
        #pragma unroll
        for (int rs = 0; rs < 2; ++rs)
            af[rs] = *reinterpret_cast<const s16x8*>(&As[32 * w + 16 * rs + c][8 * g]);
        #pragma unroll
        for (int cs = 0; cs < 4; ++cs)
            bf[cs] = *reinterpret_cast<const s16x8*>(&Bs[16 * cs + c][8 * g]);
        #pragma unroll
        for (int rs = 0; rs < 2; ++rs)
            #pragma unroll
            for (int cs = 0; cs < 4; ++cs)
                acc[rs][cs] = MFMA(af[rs], bf[cs], acc[rs][cs]);
        __syncthreads();
    }
    #pragma unroll
    for (int rs = 0; rs < 2; ++rs)
        #pragma unroll
        for (int cs = 0; cs < 4; ++cs)
            #pragma unroll
            for (int r = 0; r < 4; ++r) {
                int row = m0 + 32 * w + 16 * rs + 4 * g + r;
                int n = n0 + 16 * cs + c;
                float v = acc[rs][cs][r] + bsv[cs];
                if (mode == 0) {
                    ((float*)outp)[(size_t)row * 512 + n] = v;
                } else {
                    int bb = row >> 11, l = row & 2047, hh = n >> 6, dh = n & 63;
                    ((ushort*)outp)[(((size_t)bb * NH + hh) * L + l) * DH + dh] = f2b(v);
                }
            }
}

// ---------- fused relative attention, 2-pass recompute ----------
// wg = (bh, pair): i-blocks {pair, 63-pair} of 32 query rows each.
// Pass A: S tiles via MFMA, per-wave online (m,l) in registers, one merge.
// Pass B: recompute S, p = exp(s-m)/l, write final weights + PV MFMA.
__global__ __launch_bounds__(256, 3)
void attn(const ushort* __restrict__ qws, const ushort* __restrict__ kws,
          const ushort* __restrict__ vws, const ushort* __restrict__ Ebf,
          float* __restrict__ attnw, ushort* __restrict__ ows) {
    __shared__ float  Tst[32][100];
    __shared__ ushort Vt[64][72];
    __shared__ ushort Ptile[32][72];
    __shared__ float  redm[4][32], reds[4][32];
    __shared__ float  mrow[32], linv[32];

    const int tid = threadIdx.x;
    const int w = tid >> 6, lane = tid & 63, g = lane >> 4, c = lane & 15;
    const int bh = blockIdx.x >> 5, pr = blockIdx.x & 31;
    const int b = bh >> 3, h = bh & 7;
    const ushort* qb = qws + (size_t)bh * L * DH;
    const ushort* kb = kws + (size_t)bh * L * DH;
    const ushort* vb = vws + (size_t)bh * L * DH;
    float* ab = attnw + (size_t)bh * L * L;

    for (int rep = 0; rep < 2; ++rep) {
        const int ib = rep ? (63 - pr) : pr;
        const int i0 = ib * 32;
        const int nj = (ib >> 1) + 1;

        s16x8 aq[2][2];
        #pragma unroll
        for (int rs = 0; rs < 2; ++rs)
            #pragma unroll
            for (int ks = 0; ks < 2; ++ks)
                aq[rs][ks] = *reinterpret_cast<const s16x8*>(
                    qb + (size_t)(i0 + 16 * rs + c) * DH + 32 * ks + 8 * g);

        // compute S tile (32 rows x 64 cols at j0): rel strip + QK^T, masked, /8
        auto computeSV = [&](int j0, float (&sv)[2][4], int doV,
                             const uint4& vv0, const uint4& vv1) {
            const int rbase = L - 32 - i0 + j0;
            const int ncts = (w < 2) ? 2 : 1;
            f32x4 TT[2][2];
            for (int cti = 0; cti < ncts; ++cti) {
                int ct = w + cti * 4;
                s16x8 be[2];
                #pragma unroll
                for (int ks = 0; ks < 2; ++ks) {
                    int rg = rbase + 16 * ct + c;
                    rg = rg < 0 ? 0 : (rg > L - 1 ? L - 1 : rg);
                    be[ks] = *reinterpret_cast<const s16x8*>(
                        Ebf + (size_t)rg * DH + 32 * ks + 8 * g);
                }
                #pragma unroll
                for (int rs = 0; rs < 2; ++rs) {
                    f32x4 t = {0.f, 0.f, 0.f, 0.f};
                    t = MFMA(aq[rs][0], be[0], t);
                    t = MFMA(aq[rs][1], be[1], t);
                    TT[cti][rs] = t;
                }
            }
            f32x4 SK[2];
            {
                s16x8 bk[2];
                #pragma unroll
                for (int ks = 0; ks < 2; ++ks)
                    bk[ks] = *reinterpret_cast<const s16x8*>(
                        kb + (size_t)(j0 + 16 * w + c) * DH + 32 * ks + 8 * g);
                #pragma unroll
                for (int rs = 0; rs < 2; ++rs) {
                    f32x4 t = {0.f, 0.f, 0.f, 0.f};
                    t = MFMA(aq[rs][0], bk[0], t);
                    t = MFMA(aq[rs][1], bk[1], t);
                    SK[rs] = t;
                }
            }
            __syncthreads();              // prior tile's LDS consumers done
            for (int cti = 0; cti < ncts; ++cti) {
                int ct = w + cti * 4;
                #pragma unroll
                for (int rs = 0; rs < 2; ++rs)
                    #pragma unroll
                    for (int r = 0; r < 4; ++r)
                        Tst[16 * rs + 4 * g + r][16 * ct + c] = TT[cti][rs][r];
            }
            if (doV) {
                const int jj = tid >> 2, d8 = (tid & 3) * 16;
                const ushort* pv = (const ushort*)&vv0;
                #pragma unroll
                for (int e = 0; e < 8; ++e) Vt[d8 + e][jj] = pv[e];
                pv = (const ushort*)&vv1;
                #pragma unroll
                for (int e = 0; e < 8; ++e) Vt[d8 + 8 + e][jj] = pv[e];
            }
            __syncthreads();              // Tst (and Vt) visible
            #pragma unroll
            for (int rs = 0; rs < 2; ++rs)
                #pragma unroll
                for (int r = 0; r < 4; ++r) {
                    int il = 16 * rs + 4 * g + r;
                    int jl = 16 * w + c;
                    float s = (SK[rs][r] + Tst[il][31 + jl - il]) * 0.125f;
                    sv[rs][r] = (j0 + jl <= i0 + il) ? s : -1.0e30f;
                }
        };

        // ---------------- Pass A: softmax stats, no barriers beyond computeSV
        float mw[2][4], lw[2][4];
        #pragma unroll
        for (int rs = 0; rs < 2; ++rs)
            #pragma unroll
            for (int r = 0; r < 4; ++r) { mw[rs][r] = -1.0e30f; lw[rs][r] = 0.f; }
        uint4 zu = {0, 0, 0, 0};
        for (int tj = 0; tj < nj; ++tj) {
            float sv[2][4];
            computeSV(tj * 64, sv, 0, zu, zu);
            #pragma unroll
            for (int rs = 0; rs < 2; ++rs)
                #pragma unroll
                for (int r = 0; r < 4; ++r) {
                    float tm = sv[rs][r];
                    tm = fmaxf(tm, __shfl_xor(tm, 1));
                    tm = fmaxf(tm, __shfl_xor(tm, 2));
                    tm = fmaxf(tm, __shfl_xor(tm, 4));
                    tm = fmaxf(tm, __shfl_xor(tm, 8));
                    float mn = fmaxf(mw[rs][r], tm);
                    float pe = __expf(sv[rs][r] - mn);
                    pe += __shfl_xor(pe, 1);
                    pe += __shfl_xor(pe, 2);
                    pe += __shfl_xor(pe, 4);
                    pe += __shfl_xor(pe, 8);
                    lw[rs][r] = lw[rs][r] * __expf(mw[rs][r] - mn) + pe;
                    mw[rs][r] = mn;
                }
        }
        // cross-wave merge (once per i-block)
        if (c == 0) {
            #pragma unroll
            for (int rs = 0; rs < 2; ++rs)
                #pragma unroll
                for (int r = 0; r < 4; ++r) {
                    int il = 16 * rs + 4 * g + r;
                    redm[w][il] = mw[rs][r];
                    reds[w][il] = lw[rs][r];
                }
        }
        __syncthreads();
        if (tid < 32) {
            float m0 = redm[0][tid], m1 = redm[1][tid];
            float m2 = redm[2][tid], m3 = redm[3][tid];
            float m = fmaxf(fmaxf(m0, m1), fmaxf(m2, m3));
            float l = reds[0][tid] * __expf(m0 - m) + reds[1][tid] * __expf(m1 - m)
                    + reds[2][tid] * __expf(m2 - m) + reds[3][tid] * __expf(m3 - m);
            mrow[tid] = m;
            linv[tid] = 1.0f / l;
        }
        __syncthreads();
        float mym[2][4], myi[2][4];
        #pragma unroll
        for (int rs = 0; rs < 2; ++rs)
            #pragma unroll
            for (int r = 0; r < 4; ++r) {
                int il = 16 * rs + 4 * g + r;
                mym[rs][r] = mrow[il];
                myi[rs][r] = linv[il];
            }

        // ---------------- Pass B: recompute, final write + PV
        f32x4 O0 = {0.f, 0.f, 0.f, 0.f}, O1 = {0.f, 0.f, 0.f, 0.f};
        for (int tj = 0; tj < nj; ++tj) {
            const int j0 = tj * 64;
            uint4 vv0, vv1;
            {
                const int jj = tid >> 2, d8 = (tid & 3) * 16;
                const ushort* vp = vb + (size_t)(j0 + jj) * DH + d8;
                vv0 = *reinterpret_cast<const uint4*>(vp);
                vv1 = *reinterpret_cast<const uint4*>(vp + 8);
            }
            float sv[2][4];
            computeSV(j0, sv, 1, vv0, vv1);
            #pragma unroll
            for (int rs = 0; rs < 2; ++rs)
                #pragma unroll
                for (int r = 0; r < 4; ++r) {
                    int il = 16 * rs + 4 * g + r;
                    float p = __expf(sv[rs][r] - mym[rs][r]) * myi[rs][r];
                    Ptile[il][16 * w + c] = f2b(p);
                }
            __syncthreads();              // Ptile visible
            {   // final normalized weights for this tile (float4, coalesced)
                const int row = tid >> 3, c8 = (tid & 7) * 8;
                ushort4 u0 = *reinterpret_cast<const ushort4*>(&Ptile[row][c8]);
                ushort4 u1 = *reinterpret_cast<const ushort4*>(&Ptile[row][c8 + 4]);
                float4 f0 = make_float4(b2f(u0.x), b2f(u0.y), b2f(u0.z), b2f(u0.w));
                float4 f1 = make_float4(b2f(u1.x), b2f(u1.y), b2f(u1.z), b2f(u1.w));
                float* dst = &ab[(size_t)(i0 + row) * L + j0 + c8];
                *reinterpret_cast<float4*>(dst) = f0;
                *reinterpret_cast<float4*>(dst + 4) = f1;
            }
            #pragma unroll
            for (int ks = 0; ks < 2; ++ks) {
                s16x8 bv = *reinterpret_cast<const s16x8*>(&Vt[16 * w + c][32 * ks + 8 * g]);
                s16x8 pa0 = *reinterpret_cast<const s16x8*>(&Ptile[c][32 * ks + 8 * g]);
                s16x8 pa1 = *reinterpret_cast<const s16x8*>(&Ptile[16 + c][32 * ks + 8 * g]);
                O0 = MFMA(pa0, bv, O0);
                O1 = MFMA(pa1, bv, O1);
            }
        }

        // zero region beyond last computed tile
        {
            const int row = tid >> 3, c8 = (tid & 7) * 8;
            const float4 z = make_float4(0.f, 0.f, 0.f, 0.f);
            for (int j0 = nj * 64; j0 < L; j0 += 64) {
                float* dst = &ab[(size_t)(i0 + row) * L + j0 + c8];
                *reinterpret_cast<float4*>(dst) = z;
                *reinterpret_cast<float4*>(dst + 4) = z;
            }
        }

        // O (already normalized) -> ows bf16 (B,L,D)
        #pragma unroll
        for (int rs = 0; rs < 2; ++rs)
            #pragma unroll
            for (int r = 0; r < 4; ++r) {
                int il = 16 * rs + 4 * g + r;
                float v = (rs ? O1[r] : O0[r]);
                ows[((size_t)b * L + i0 + il) * DMODEL + h * DH + 16 * w + c] = f2b(v);
            }
    } // rep
}

extern "C" void kernel_launch(void* const* d_in, const int* in_sizes, int n_in,
                              void* d_out, int out_size, void* d_ws, size_t ws_size,
                              hipStream_t stream) {
    const float* q_in = (const float*)d_in[0];
    const float* k_in = (const float*)d_in[1];
    const float* v_in = (const float*)d_in[2];
    const float* Wq  = (const float*)d_in[4];
    const float* bq  = (const float*)d_in[5];
    const float* Wk  = (const float*)d_in[6];
    const float* bk  = (const float*)d_in[7];
    const float* Wv  = (const float*)d_in[8];
    const float* bv  = (const float*)d_in[9];
    const float* Wfc = (const float*)d_in[10];
    const float* bfc = (const float*)d_in[11];
    const float* E   = (const float*)d_in[12];

    float* out0  = (float*)d_out;                        // (B,L,D) f32
    float* attnw = out0 + (size_t)2 * L * DMODEL;        // (B,H,L,L) f32

    const size_t NA = (size_t)NROWS * DMODEL;            // 2,097,152
    ushort* ws = (ushort*)d_ws;
    ushort* qx   = ws;
    ushort* kx   = qx + NA;
    ushort* vx   = kx + NA;
    ushort* Ebf  = vx + NA;                              // 131072
    ushort* Wqt  = Ebf + (size_t)L * DH;
    ushort* Wkt  = Wqt + 262144;
    ushort* Wvt  = Wkt + 262144;
    ushort* Wfct = Wvt + 262144;
    ushort* qws  = Wfct + 262144;
    ushort* kws  = qws + NA;
    ushort* vws  = kws + NA;
    ushort* ows  = vws + NA;

    cvt_bf16<<<dim3(1024), 256, 0, stream>>>(q_in, qx, (int)(NA / 8));
    cvt_bf16<<<dim3(1024), 256, 0, stream>>>(k_in, kx, (int)(NA / 8));
    cvt_bf16<<<dim3(1024), 256, 0, stream>>>(v_in, vx, (int)(NA / 8));
    cvt_bf16<<<dim3(64), 256, 0, stream>>>(E, Ebf, (int)(L * DH / 8));
    transpose_w<<<dim3(8, 8, 4), 256, 0, stream>>>(Wq, Wk, Wv, Wfc, Wqt, Wkt, Wvt, Wfct);
    gemm_bf16<<<dim3(8, 32, 3), 256, 0, stream>>>(qx, kx, vx, Wqt, Wkt, Wvt,
                                                  bq, bk, bv, qws, kws, vws, 1);
    attn<<<dim3(512), 256, 0, stream>>>(qws, kws, vws, Ebf, attnw, ows);
    gemm_bf16<<<dim3(8, 32, 1), 256, 0, stream>>>(ows, ows, ows, Wfct, Wfct, Wfct,
                                                  bfc, bfc, bfc, out0, out0, out0, 0);
}

// Round 4
// 240.570 us; speedup vs baseline: 3.4066x; 1.1846x over previous
//
#include <hip/hip_runtime.h>
#include <math.h>

#define L 2048
#define DMODEL 512
#define NH 8
#define DH 64
#define NROWS 4096   // B*L

typedef __attribute__((ext_vector_type(4))) float f32x4;
typedef __attribute__((ext_vector_type(8))) short s16x8;

#define MFMA(a, b, c) __builtin_amdgcn_mfma_f32_16x16x32_bf16(a, b, c, 0, 0, 0)

static __device__ __forceinline__ ushort f2b(float f) {
    union { float f; unsigned u; } v; v.f = f;
    unsigned r = v.u + 0x7FFF + ((v.u >> 16) & 1);
    return (ushort)(r >> 16);
}
static __device__ __forceinline__ float b2f(ushort u) {
    union { unsigned u; float f; } v; v.u = ((unsigned)u) << 16;
    return v.f;
}

// ---------- f32 -> bf16 convert (8 elems/thread) ----------
__global__ __launch_bounds__(256)
void cvt_bf16(const float* __restrict__ in, ushort* __restrict__ out, int n8) {
    int i = blockIdx.x * 256 + threadIdx.x;
    if (i < n8) {
        float4 a = *reinterpret_cast<const float4*>(&in[(size_t)i * 8]);
        float4 b = *reinterpret_cast<const float4*>(&in[(size_t)i * 8 + 4]);
        ushort4 o0; o0.x = f2b(a.x); o0.y = f2b(a.y); o0.z = f2b(a.z); o0.w = f2b(a.w);
        ushort4 o1; o1.x = f2b(b.x); o1.y = f2b(b.y); o1.z = f2b(b.z); o1.w = f2b(b.w);
        *reinterpret_cast<ushort4*>(&out[(size_t)i * 8]) = o0;
        *reinterpret_cast<ushort4*>(&out[(size_t)i * 8 + 4]) = o1;
    }
}

// ---------- W (512x512 f32, row-major [k][n]) -> Wt bf16 [n][k] ----------
__global__ __launch_bounds__(256)
void transpose_w(const float* __restrict__ W0, const float* __restrict__ W1,
                 const float* __restrict__ W2, const float* __restrict__ W3,
                 ushort* __restrict__ T0, ushort* __restrict__ T1,
                 ushort* __restrict__ T2, ushort* __restrict__ T3) {
    const int z = blockIdx.z;
    const float* W = z == 0 ? W0 : (z == 1 ? W1 : (z == 2 ? W2 : W3));
    ushort* T = z == 0 ? T0 : (z == 1 ? T1 : (z == 2 ? T2 : T3));
    __shared__ float Ls[64][65];
    const int tid = threadIdx.x;
    const int k0 = blockIdx.y * 64, n0 = blockIdx.x * 64;
    #pragma unroll
    for (int i = 0; i < 4; ++i) {
        int kk = (tid >> 4) + i * 16, n4 = (tid & 15) * 4;
        float4 v = *reinterpret_cast<const float4*>(&W[(size_t)(k0 + kk) * 512 + n0 + n4]);
        Ls[kk][n4] = v.x; Ls[kk][n4 + 1] = v.y; Ls[kk][n4 + 2] = v.z; Ls[kk][n4 + 3] = v.w;
    }
    __syncthreads();
    #pragma unroll
    for (int i = 0; i < 4; ++i) {
        int nn = (tid >> 4) + i * 16, k4 = (tid & 15) * 4;
        ushort4 o;
        o.x = f2b(Ls[k4 + 0][nn]); o.y = f2b(Ls[k4 + 1][nn]);
        o.z = f2b(Ls[k4 + 2][nn]); o.w = f2b(Ls[k4 + 3][nn]);
        *reinterpret_cast<ushort4*>(&T[(size_t)(n0 + nn) * 512 + k0 + k4]) = o;
    }
}

// ---------- bf16 MFMA GEMM: out = A(4096x512) @ Wt^T + bias ----------
// a_f32: A operand is f32 (converted during staging). mode 0: f32 row-major
// out. mode 1: bf16 scatter to (B,H,L,DH).
__global__ __launch_bounds__(256)
void gemm_bf16(const void* __restrict__ A0, const void* __restrict__ A1,
               const void* __restrict__ A2,
               const ushort* __restrict__ W0, const ushort* __restrict__ W1,
               const ushort* __restrict__ W2,
               const float* __restrict__ b0, const float* __restrict__ b1,
               const float* __restrict__ b2,
               void* o0, void* o1, void* o2, int a_f32, int mode) {
    const int z = blockIdx.z;
    const void* A   = z == 0 ? A0 : (z == 1 ? A1 : A2);
    const ushort* Wt = z == 0 ? W0 : (z == 1 ? W1 : W2);
    const float* bias = z == 0 ? b0 : (z == 1 ? b1 : b2);
    void* outp = z == 0 ? o0 : (z == 1 ? o1 : o2);

    __shared__ ushort As[128][40];
    __shared__ ushort Bs[64][40];
    const int tid = threadIdx.x;
    const int w = tid >> 6, lane = tid & 63, g = lane >> 4, c = lane & 15;
    const int m0 = blockIdx.y * 128, n0 = blockIdx.x * 64;

    f32x4 acc[2][4];
    #pragma unroll
    for (int rs = 0; rs < 2; ++rs)
        #pragma unroll
        for (int cs = 0; cs < 4; ++cs) acc[rs][cs] = (f32x4){0.f, 0.f, 0.f, 0.f};

    float bsv[4];
    #pragma unroll
    for (int cs = 0; cs < 4; ++cs) bsv[cs] = bias[n0 + 16 * cs + c];

    for (int k0 = 0; k0 < 512; k0 += 32) {
        {
            int row = tid >> 1, kh = (tid & 1) * 16;
            if (a_f32) {
                const float* p = (const float*)A + (size_t)(m0 + row) * 512 + k0 + kh;
                ushort tmp[16];
                #pragma unroll
                for (int q4 = 0; q4 < 4; ++q4) {
                    float4 f = *reinterpret_cast<const float4*>(p + q4 * 4);
                    tmp[q4 * 4 + 0] = f2b(f.x); tmp[q4 * 4 + 1] = f2b(f.y);
                    tmp[q4 * 4 + 2] = f2b(f.z); tmp[q4 * 4 + 3] = f2b(f.w);
                }
                *reinterpret_cast<uint4*>(&As[row][kh]) = *reinterpret_cast<uint4*>(&tmp[0]);
                *reinterpret_cast<uint4*>(&As[row][kh + 8]) = *reinterpret_cast<uint4*>(&tmp[8]);
            } else {
                const ushort* p = (const ushort*)A + (size_t)(m0 + row) * 512 + k0 + kh;
                uint4 x0 = *reinterpret_cast<const uint4*>(p);
                uint4 x1 = *reinterpret_cast<const uint4*>(p + 8);
                *reinterpret_cast<uint4*>(&As[row][kh]) = x0;
                *reinterpret_cast<uint4*>(&As[row][kh + 8]) = x1;
            }
        }
        {
            int n = tid >> 2, kh = (tid & 3) * 8;
            uint4 x = *reinterpret_cast<const uint4*>(&Wt[(size_t)(n0 + n) * 512 + k0 + kh]);
            *reinterpret_cast<uint4*>(&Bs[n][kh]) = x;
        }
        __syncthreads();
        s16x8 af[2], bf[4];
        #pragma unroll
        for (int rs = 0; rs < 2; ++rs)
            af[rs] = *reinterpret_cast<const s16x8*>(&As[32 * w + 16 * rs + c][8 * g]);
        #pragma unroll
        for (int cs = 0; cs < 4; ++cs)
            bf[cs] = *reinterpret_cast<const s16x8*>(&Bs[16 * cs + c][8 * g]);
        #pragma unroll
        for (int rs = 0; rs < 2; ++rs)
            #pragma unroll
            for (int cs = 0; cs < 4; ++cs)
                acc[rs][cs] = MFMA(af[rs], bf[cs], acc[rs][cs]);
        __syncthreads();
    }
    #pragma unroll
    for (int rs = 0; rs < 2; ++rs)
        #pragma unroll
        for (int cs = 0; cs < 4; ++cs)
            #pragma unroll
            for (int r = 0; r < 4; ++r) {
                int row = m0 + 32 * w + 16 * rs + 4 * g + r;
                int n = n0 + 16 * cs + c;
                float v = acc[rs][cs][r] + bsv[cs];
                if (mode == 0) {
                    ((float*)outp)[(size_t)row * 512 + n] = v;
                } else {
                    int bb = row >> 11, l = row & 2047, hh = n >> 6, dh = n & 63;
                    ((ushort*)outp)[(((size_t)bb * NH + hh) * L + l) * DH + dh] = f2b(v);
                }
            }
}

// ---------- fused relative attention, 2-pass recompute ----------
// One wg per (bh, 32-row i-block), heavy blocks dispatched first.
// Pass A: S via MFMA, per-LANE online (m,l) (no cross-lane in loop), 1 bar/tile.
// Pass B: recompute S, p = exp(s-m)/l, final-weight write + PV MFMA, 2 bar/tile.
__global__ __launch_bounds__(256, 3)
void attn(const ushort* __restrict__ qws, const ushort* __restrict__ kws,
          const ushort* __restrict__ vws, const ushort* __restrict__ Ebf,
          float* __restrict__ attnw, ushort* __restrict__ ows) {
    __shared__ float  Tst[2][32][100];
    __shared__ ushort Vt[2][64][68];
    __shared__ ushort Ptile[2][32][68];
    __shared__ float  redm[4][32], reds[4][32];
    __shared__ float  mrow[32], linv[32];

    const int tid = threadIdx.x;
    const int w = tid >> 6, lane = tid & 63, g = lane >> 4, c = lane & 15;
    const int bid = blockIdx.x;
    const int bh = bid & 15;
    const int ib = 63 - (bid >> 4);           // heavy-first
    const int b = bh >> 3, h = bh & 7;
    const int i0 = ib * 32;
    const int nj = (ib >> 1) + 1;

    const ushort* qb = qws + (size_t)bh * L * DH;
    const ushort* kb = kws + (size_t)bh * L * DH;
    const ushort* vb = vws + (size_t)bh * L * DH;
    float* ab = attnw + (size_t)bh * L * L;

    s16x8 aq[2][2];
    #pragma unroll
    for (int rs = 0; rs < 2; ++rs)
        #pragma unroll
        for (int ks = 0; ks < 2; ++ks)
            aq[rs][ks] = *reinterpret_cast<const s16x8*>(
                qb + (size_t)(i0 + 16 * rs + c) * DH + 32 * ks + 8 * g);

    // S tile (32 x 64 at j0): rel strip + QK^T, masked, /8.  ONE barrier.
    auto computeS = [&](int j0, int buf, float (&sv)[2][4], int doV,
                        const uint4& vv0, const uint4& vv1) {
        const int rbase = L - 32 - i0 + j0;
        const int ncts = (w < 2) ? 2 : 1;
        f32x4 TT[2][2];
        for (int cti = 0; cti < ncts; ++cti) {
            int ct = w + cti * 4;
            s16x8 be[2];
            #pragma unroll
            for (int ks = 0; ks < 2; ++ks) {
                int rg = rbase + 16 * ct + c;
                rg = rg < 0 ? 0 : (rg > L - 1 ? L - 1 : rg);
                be[ks] = *reinterpret_cast<const s16x8*>(
                    Ebf + (size_t)rg * DH + 32 * ks + 8 * g);
            }
            #pragma unroll
            for (int rs = 0; rs < 2; ++rs) {
                f32x4 t = {0.f, 0.f, 0.f, 0.f};
                t = MFMA(aq[rs][0], be[0], t);
                t = MFMA(aq[rs][1], be[1], t);
                TT[cti][rs] = t;
            }
        }
        f32x4 SK[2];
        {
            s16x8 bk[2];
            #pragma unroll
            for (int ks = 0; ks < 2; ++ks)
                bk[ks] = *reinterpret_cast<const s16x8*>(
                    kb + (size_t)(j0 + 16 * w + c) * DH + 32 * ks + 8 * g);
            #pragma unroll
            for (int rs = 0; rs < 2; ++rs) {
                f32x4 t = {0.f, 0.f, 0.f, 0.f};
                t = MFMA(aq[rs][0], bk[0], t);
                t = MFMA(aq[rs][1], bk[1], t);
                SK[rs] = t;
            }
        }
        for (int cti = 0; cti < ncts; ++cti) {
            int ct = w + cti * 4;
            #pragma unroll
            for (int rs = 0; rs < 2; ++rs)
                #pragma unroll
                for (int r = 0; r < 4; ++r)
                    Tst[buf][16 * rs + 4 * g + r][16 * ct + c] = TT[cti][rs][r];
        }
        if (doV) {
            const int jj = tid >> 2, d8 = (tid & 3) * 16;
            const ushort* pv = (const ushort*)&vv0;
            #pragma unroll
            for (int e = 0; e < 8; ++e) Vt[buf][d8 + e][jj] = pv[e];
            pv = (const ushort*)&vv1;
            #pragma unroll
            for (int e = 0; e < 8; ++e) Vt[buf][d8 + 8 + e][jj] = pv[e];
        }
        __syncthreads();              // T (and V) visible; dbuf guards reuse
        #pragma unroll
        for (int rs = 0; rs < 2; ++rs)
            #pragma unroll
            for (int r = 0; r < 4; ++r) {
                int il = 16 * rs + 4 * g + r;
                int jl = 16 * w + c;
                float s = (SK[rs][r] + Tst[buf][il][31 + jl - il]) * 0.125f;
                sv[rs][r] = (j0 + jl <= i0 + il) ? s : -1.0e30f;
            }
    };

    // ---------------- Pass A: per-lane online stats ----------------
    float mw[2][4], lw[2][4];
    #pragma unroll
    for (int rs = 0; rs < 2; ++rs)
        #pragma unroll
        for (int r = 0; r < 4; ++r) { mw[rs][r] = -1.0e30f; lw[rs][r] = 0.f; }
    uint4 zu = {0, 0, 0, 0};
    for (int tj = 0; tj < nj; ++tj) {
        float sv[2][4];
        computeS(tj * 64, tj & 1, sv, 0, zu, zu);
        #pragma unroll
        for (int rs = 0; rs < 2; ++rs)
            #pragma unroll
            for (int r = 0; r < 4; ++r) {
                float s = sv[rs][r];
                float mn = fmaxf(mw[rs][r], s);
                lw[rs][r] = lw[rs][r] * __expf(mw[rs][r] - mn) + __expf(s - mn);
                mw[rs][r] = mn;
            }
    }
    // lane merge across the 16 cols sharing a row (shfl), then cross-wave
    #pragma unroll
    for (int rs = 0; rs < 2; ++rs)
        #pragma unroll
        for (int r = 0; r < 4; ++r) {
            float m = mw[rs][r], l = lw[rs][r];
            #pragma unroll
            for (int d = 1; d < 16; d <<= 1) {
                float om = __shfl_xor(m, d);
                float ol = __shfl_xor(l, d);
                float mn = fmaxf(m, om);
                l = l * __expf(m - mn) + ol * __expf(om - mn);
                m = mn;
            }
            if (c == 0) {
                int il = 16 * rs + 4 * g + r;
                redm[w][il] = m;
                reds[w][il] = l;
            }
        }
    __syncthreads();
    if (tid < 32) {
        float m0 = redm[0][tid], m1 = redm[1][tid];
        float m2 = redm[2][tid], m3 = redm[3][tid];
        float m = fmaxf(fmaxf(m0, m1), fmaxf(m2, m3));
        float l = reds[0][tid] * __expf(m0 - m) + reds[1][tid] * __expf(m1 - m)
                + reds[2][tid] * __expf(m2 - m) + reds[3][tid] * __expf(m3 - m);
        mrow[tid] = m;
        linv[tid] = 1.0f / l;
    }
    __syncthreads();
    float mym[2][4], myi[2][4];
    #pragma unroll
    for (int rs = 0; rs < 2; ++rs)
        #pragma unroll
        for (int r = 0; r < 4; ++r) {
            int il = 16 * rs + 4 * g + r;
            mym[rs][r] = mrow[il];
            myi[rs][r] = linv[il];
        }

    // ---------------- Pass B: recompute, final write + PV ----------------
    f32x4 O0 = {0.f, 0.f, 0.f, 0.f}, O1 = {0.f, 0.f, 0.f, 0.f};
    for (int tj = 0; tj < nj; ++tj) {
        const int j0 = tj * 64;
        const int buf = tj & 1;
        uint4 vv0, vv1;
        {
            const int jj = tid >> 2, d8 = (tid & 3) * 16;
            const ushort* vp = vb + (size_t)(j0 + jj) * DH + d8;
            vv0 = *reinterpret_cast<const uint4*>(vp);
            vv1 = *reinterpret_cast<const uint4*>(vp + 8);
        }
        float sv[2][4];
        computeS(j0, buf, sv, 1, vv0, vv1);
        #pragma unroll
        for (int rs = 0; rs < 2; ++rs)
            #pragma unroll
            for (int r = 0; r < 4; ++r) {
                int il = 16 * rs + 4 * g + r;
                float p = __expf(sv[rs][r] - mym[rs][r]) * myi[rs][r];
                Ptile[buf][il][16 * w + c] = f2b(p);
            }
        __syncthreads();              // Ptile visible
        {   // final normalized weights (coalesced float4 x2 per thread)
            const int row = tid >> 3, c8 = (tid & 7) * 8;
            ushort4 u0 = *reinterpret_cast<const ushort4*>(&Ptile[buf][row][c8]);
            ushort4 u1 = *reinterpret_cast<const ushort4*>(&Ptile[buf][row][c8 + 4]);
            float4 f0 = make_float4(b2f(u0.x), b2f(u0.y), b2f(u0.z), b2f(u0.w));
            float4 f1 = make_float4(b2f(u1.x), b2f(u1.y), b2f(u1.z), b2f(u1.w));
            float* dst = &ab[(size_t)(i0 + row) * L + j0 + c8];
            *reinterpret_cast<float4*>(dst) = f0;
            *reinterpret_cast<float4*>(dst + 4) = f1;
        }
        #pragma unroll
        for (int ks = 0; ks < 2; ++ks) {
            s16x8 bv = *reinterpret_cast<const s16x8*>(&Vt[buf][16 * w + c][32 * ks + 8 * g]);
            s16x8 pa0 = *reinterpret_cast<const s16x8*>(&Ptile[buf][c][32 * ks + 8 * g]);
            s16x8 pa1 = *reinterpret_cast<const s16x8*>(&Ptile[buf][16 + c][32 * ks + 8 * g]);
            O0 = MFMA(pa0, bv, O0);
            O1 = MFMA(pa1, bv, O1);
        }
    }

    // zero region beyond last computed tile
    {
        const int row = tid >> 3, c8 = (tid & 7) * 8;
        const float4 z = make_float4(0.f, 0.f, 0.f, 0.f);
        for (int j0 = nj * 64; j0 < L; j0 += 64) {
            float* dst = &ab[(size_t)(i0 + row) * L + j0 + c8];
            *reinterpret_cast<float4*>(dst) = z;
            *reinterpret_cast<float4*>(dst + 4) = z;
        }
    }

    // O (already normalized) -> ows bf16 (B,L,D)
    #pragma unroll
    for (int rs = 0; rs < 2; ++rs)
        #pragma unroll
        for (int r = 0; r < 4; ++r) {
            int il = 16 * rs + 4 * g + r;
            float v = (rs ? O1[r] : O0[r]);
            ows[((size_t)b * L + i0 + il) * DMODEL + h * DH + 16 * w + c] = f2b(v);
        }
}

extern "C" void kernel_launch(void* const* d_in, const int* in_sizes, int n_in,
                              void* d_out, int out_size, void* d_ws, size_t ws_size,
                              hipStream_t stream) {
    const float* q_in = (const float*)d_in[0];
    const float* k_in = (const float*)d_in[1];
    const float* v_in = (const float*)d_in[2];
    const float* Wq  = (const float*)d_in[4];
    const float* bq  = (const float*)d_in[5];
    const float* Wk  = (const float*)d_in[6];
    const float* bk  = (const float*)d_in[7];
    const float* Wv  = (const float*)d_in[8];
    const float* bv  = (const float*)d_in[9];
    const float* Wfc = (const float*)d_in[10];
    const float* bfc = (const float*)d_in[11];
    const float* E   = (const float*)d_in[12];

    float* out0  = (float*)d_out;                        // (B,L,D) f32
    float* attnw = out0 + (size_t)2 * L * DMODEL;        // (B,H,L,L) f32

    const size_t NA = (size_t)NROWS * DMODEL;            // 2,097,152
    ushort* ws = (ushort*)d_ws;
    ushort* Ebf  = ws;                                   // 131072
    ushort* Wqt  = Ebf + (size_t)L * DH;
    ushort* Wkt  = Wqt + 262144;
    ushort* Wvt  = Wkt + 262144;
    ushort* Wfct = Wvt + 262144;
    ushort* qws  = Wfct + 262144;
    ushort* kws  = qws + NA;
    ushort* vws  = kws + NA;
    ushort* ows  = vws + NA;

    cvt_bf16<<<dim3(64), 256, 0, stream>>>(E, Ebf, (int)(L * DH / 8));
    transpose_w<<<dim3(8, 8, 4), 256, 0, stream>>>(Wq, Wk, Wv, Wfc, Wqt, Wkt, Wvt, Wfct);
    gemm_bf16<<<dim3(8, 32, 3), 256, 0, stream>>>(q_in, k_in, v_in, Wqt, Wkt, Wvt,
                                                  bq, bk, bv, qws, kws, vws, 1, 1);
    attn<<<dim3(1024), 256, 0, stream>>>(qws, kws, vws, Ebf, attnw, ows);
    gemm_bf16<<<dim3(8, 32, 1), 256, 0, stream>>>(ows, ows, ows, Wfct, Wfct, Wfct,
                                                  bfc, bfc, bfc, out0, out0, out0, 0, 0);
}

// Round 5
// 216.143 us; speedup vs baseline: 3.7916x; 1.1130x over previous
//
#include <hip/hip_runtime.h>
#include <math.h>

#define L 2048
#define DMODEL 512
#define NH 8
#define DH 64
#define NROWS 4096   // B*L

typedef __attribute__((ext_vector_type(4))) float f32x4;
typedef __attribute__((ext_vector_type(8))) short s16x8;

#define MFMA(a, b, c) __builtin_amdgcn_mfma_f32_16x16x32_bf16(a, b, c, 0, 0, 0)

static __device__ __forceinline__ ushort f2b(float f) {
    union { float f; unsigned u; } v; v.f = f;
    unsigned r = v.u + 0x7FFF + ((v.u >> 16) & 1);
    return (ushort)(r >> 16);
}

// ---------- f32 -> bf16 convert (8 elems/thread) ----------
__global__ __launch_bounds__(256)
void cvt_bf16(const float* __restrict__ in, ushort* __restrict__ out, int n8) {
    int i = blockIdx.x * 256 + threadIdx.x;
    if (i < n8) {
        float4 a = *reinterpret_cast<const float4*>(&in[(size_t)i * 8]);
        float4 b = *reinterpret_cast<const float4*>(&in[(size_t)i * 8 + 4]);
        ushort4 o0; o0.x = f2b(a.x); o0.y = f2b(a.y); o0.z = f2b(a.z); o0.w = f2b(a.w);
        ushort4 o1; o1.x = f2b(b.x); o1.y = f2b(b.y); o1.z = f2b(b.z); o1.w = f2b(b.w);
        *reinterpret_cast<ushort4*>(&out[(size_t)i * 8]) = o0;
        *reinterpret_cast<ushort4*>(&out[(size_t)i * 8 + 4]) = o1;
    }
}

// ---------- W (512x512 f32, row-major [k][n]) -> Wt bf16 [n][k] ----------
__global__ __launch_bounds__(256)
void transpose_w(const float* __restrict__ W0, const float* __restrict__ W1,
                 const float* __restrict__ W2, const float* __restrict__ W3,
                 ushort* __restrict__ T0, ushort* __restrict__ T1,
                 ushort* __restrict__ T2, ushort* __restrict__ T3) {
    const int z = blockIdx.z;
    const float* W = z == 0 ? W0 : (z == 1 ? W1 : (z == 2 ? W2 : W3));
    ushort* T = z == 0 ? T0 : (z == 1 ? T1 : (z == 2 ? T2 : T3));
    __shared__ float Ls[64][65];
    const int tid = threadIdx.x;
    const int k0 = blockIdx.y * 64, n0 = blockIdx.x * 64;
    #pragma unroll
    for (int i = 0; i < 4; ++i) {
        int kk = (tid >> 4) + i * 16, n4 = (tid & 15) * 4;
        float4 v = *reinterpret_cast<const float4*>(&W[(size_t)(k0 + kk) * 512 + n0 + n4]);
        Ls[kk][n4] = v.x; Ls[kk][n4 + 1] = v.y; Ls[kk][n4 + 2] = v.z; Ls[kk][n4 + 3] = v.w;
    }
    __syncthreads();
    #pragma unroll
    for (int i = 0; i < 4; ++i) {
        int nn = (tid >> 4) + i * 16, k4 = (tid & 15) * 4;
        ushort4 o;
        o.x = f2b(Ls[k4 + 0][nn]); o.y = f2b(Ls[k4 + 1][nn]);
        o.z = f2b(Ls[k4 + 2][nn]); o.w = f2b(Ls[k4 + 3][nn]);
        *reinterpret_cast<ushort4*>(&T[(size_t)(n0 + nn) * 512 + k0 + k4]) = o;
    }
}

// ---------- bf16 MFMA GEMM: out = A(4096x512) @ Wt^T + bias ----------
// a_f32: A operand is f32 (converted during staging).
// mode 0: f32 row-major out. mode 1: bf16 scatter (B,H,L,DH).
// mode 2: bf16 transposed scatter (B,H,DH,L)  [for V^T].
__global__ __launch_bounds__(256)
void gemm_bf16(const void* __restrict__ A0, const void* __restrict__ A1,
               const ushort* __restrict__ W0, const ushort* __restrict__ W1,
               const float* __restrict__ b0, const float* __restrict__ b1,
               void* o0, void* o1, int a_f32, int mode) {
    const int z = blockIdx.z;
    const void* A   = z == 0 ? A0 : A1;
    const ushort* Wt = z == 0 ? W0 : W1;
    const float* bias = z == 0 ? b0 : b1;
    void* outp = z == 0 ? o0 : o1;

    __shared__ ushort As[128][40];
    __shared__ ushort Bs[64][40];
    const int tid = threadIdx.x;
    const int w = tid >> 6, lane = tid & 63, g = lane >> 4, c = lane & 15;
    const int m0 = blockIdx.y * 128, n0 = blockIdx.x * 64;

    f32x4 acc[2][4];
    #pragma unroll
    for (int rs = 0; rs < 2; ++rs)
        #pragma unroll
        for (int cs = 0; cs < 4; ++cs) acc[rs][cs] = (f32x4){0.f, 0.f, 0.f, 0.f};

    float bsv[4];
    #pragma unroll
    for (int cs = 0; cs < 4; ++cs) bsv[cs] = bias[n0 + 16 * cs + c];

    for (int k0 = 0; k0 < 512; k0 += 32) {
        {
            int row = tid >> 1, kh = (tid & 1) * 16;
            if (a_f32) {
                const float* p = (const float*)A + (size_t)(m0 + row) * 512 + k0 + kh;
                ushort tmp[16];
                #pragma unroll
                for (int q4 = 0; q4 < 4; ++q4) {
                    float4 f = *reinterpret_cast<const float4*>(p + q4 * 4);
                    tmp[q4 * 4 + 0] = f2b(f.x); tmp[q4 * 4 + 1] = f2b(f.y);
                    tmp[q4 * 4 + 2] = f2b(f.z); tmp[q4 * 4 + 3] = f2b(f.w);
                }
                *reinterpret_cast<uint4*>(&As[row][kh]) = *reinterpret_cast<uint4*>(&tmp[0]);
                *reinterpret_cast<uint4*>(&As[row][kh + 8]) = *reinterpret_cast<uint4*>(&tmp[8]);
            } else {
                const ushort* p = (const ushort*)A + (size_t)(m0 + row) * 512 + k0 + kh;
                uint4 x0 = *reinterpret_cast<const uint4*>(p);
                uint4 x1 = *reinterpret_cast<const uint4*>(p + 8);
                *reinterpret_cast<uint4*>(&As[row][kh]) = x0;
                *reinterpret_cast<uint4*>(&As[row][kh + 8]) = x1;
            }
        }
        {
            int n = tid >> 2, kh = (tid & 3) * 8;
            uint4 x = *reinterpret_cast<const uint4*>(&Wt[(size_t)(n0 + n) * 512 + k0 + kh]);
            *reinterpret_cast<uint4*>(&Bs[n][kh]) = x;
        }
        __syncthreads();
        s16x8 af[2], bf[4];
        #pragma unroll
        for (int rs = 0; rs < 2; ++rs)
            af[rs] = *reinterpret_cast<const s16x8*>(&As[32 * w + 16 * rs + c][8 * g]);
        #pragma unroll
        for (int cs = 0; cs < 4; ++cs)
            bf[cs] = *reinterpret_cast<const s16x8*>(&Bs[16 * cs + c][8 * g]);
        #pragma unroll
        for (int rs = 0; rs < 2; ++rs)
            #pragma unroll
            for (int cs = 0; cs < 4; ++cs)
                acc[rs][cs] = MFMA(af[rs], bf[cs], acc[rs][cs]);
        __syncthreads();
    }
    #pragma unroll
    for (int rs = 0; rs < 2; ++rs)
        #pragma unroll
        for (int cs = 0; cs < 4; ++cs)
            #pragma unroll
            for (int r = 0; r < 4; ++r) {
                int row = m0 + 32 * w + 16 * rs + 4 * g + r;
                int n = n0 + 16 * cs + c;
                float v = acc[rs][cs][r] + bsv[cs];
                int bb = row >> 11, l = row & 2047, hh = n >> 6, dh = n & 63;
                if (mode == 0) {
                    ((float*)outp)[(size_t)row * 512 + n] = v;
                } else if (mode == 1) {
                    ((ushort*)outp)[(((size_t)bb * NH + hh) * L + l) * DH + dh] = f2b(v);
                } else {
                    ((ushort*)outp)[(((size_t)bb * NH + hh) * DH + dh) * L + l] = f2b(v);
                }
            }
}

// ---------- fused relative attention: single pass, barrier-free main loop ---
// One wg per (bh, 32-row i-block); within a wg each WAVE independently owns
// 32-col key tiles t = w, w+4, ... (no LDS sharing in the loop).
// Writes unnormalized p = exp(s) (f32) to attnw, accumulates l and O = p@V;
// a later rescale kernel applies 1/l to attnw in place.
__global__ __launch_bounds__(256, 3)
void attn(const ushort* __restrict__ qws, const ushort* __restrict__ kws,
          const ushort* __restrict__ vtg, const ushort* __restrict__ Ebf,
          float* __restrict__ attnw, ushort* __restrict__ ows,
          float* __restrict__ linvg) {
    __shared__ float Ored[4][32][68];       // also aliased as per-wave P scratch
    __shared__ float lred[4][32];
    __shared__ float linvs[32];

    const int tid = threadIdx.x;
    const int w = tid >> 6, lane = tid & 63, g = lane >> 4, c = lane & 15;
    const int bid = blockIdx.x;
    const int bh = bid & 15;
    const int ib = 63 - (bid >> 4);         // heavy-first
    const int b = bh >> 3, h = bh & 7;
    const int i0 = ib * 32;
    const int nt = ib + 1;                  // 32-col tiles

    const ushort* qb = qws + (size_t)bh * L * DH;
    const ushort* kb = kws + (size_t)bh * L * DH;
    const ushort* vt = vtg + (size_t)bh * DH * L;
    float* ab = attnw + (size_t)bh * L * L;

    // per-wave P scratch (bf16 [32][40]) aliased onto Ored[w]
    ushort (*Pw)[40] = reinterpret_cast<ushort(*)[40]>(&Ored[w][0][0]);

    s16x8 aq[2][2];
    #pragma unroll
    for (int rs = 0; rs < 2; ++rs)
        #pragma unroll
        for (int ks = 0; ks < 2; ++ks)
            aq[rs][ks] = *reinterpret_cast<const s16x8*>(
                qb + (size_t)(i0 + 16 * rs + c) * DH + 32 * ks + 8 * g);

    f32x4 O[2][4];
    #pragma unroll
    for (int rs = 0; rs < 2; ++rs)
        #pragma unroll
        for (int cs = 0; cs < 4; ++cs) O[rs][cs] = (f32x4){0.f, 0.f, 0.f, 0.f};
    float lsum[2][4] = {};

    for (int t = w; t < nt; t += 4) {
        const int j0 = t * 32;
        const int rbase = L - 32 - i0 + j0;   // E row = rbase + s, s = 31+jl-il

        // --- T strip: T[il][s] = Q . E^T, s in [0,64) (4 col-tiles) ---
        f32x4 TT[4][2];
        #pragma unroll
        for (int ct = 0; ct < 4; ++ct) {
            s16x8 be[2];
            int rg = rbase + 16 * ct + c;
            rg = rg > L - 1 ? L - 1 : rg;     // clamped rows only feed masked cols
            #pragma unroll
            for (int ks = 0; ks < 2; ++ks)
                be[ks] = *reinterpret_cast<const s16x8*>(
                    Ebf + (size_t)rg * DH + 32 * ks + 8 * g);
            #pragma unroll
            for (int rs = 0; rs < 2; ++rs) {
                f32x4 x = {0.f, 0.f, 0.f, 0.f};
                x = MFMA(aq[rs][0], be[0], x);
                x = MFMA(aq[rs][1], be[1], x);
                TT[ct][rs] = x;
            }
        }
        // --- in-wave diagonal gather: rel[rs][jh][r] = T[il][31+jl-il] ---
        float rel[2][2][4];
        #pragma unroll
        for (int r = 0; r < 4; ++r) {
            const int u = c - 4 * g - r;
            const int src = (lane & 48) | ((15 + u) & 15);
            const bool hi = (u >= 1);
            #pragma unroll
            for (int rs = 0; rs < 2; ++rs)
                #pragma unroll
                for (int jh = 0; jh < 2; ++jh) {
                    const int b0 = jh - rs + 1;
                    float va = __shfl(TT[b0][rs][r], src);
                    float vb = __shfl(TT[b0 + 1][rs][r], src);
                    rel[rs][jh][r] = hi ? vb : va;
                }
        }
        // --- QK^T ---
        f32x4 SK[2][2];
        {
            s16x8 bk[2][2];
            #pragma unroll
            for (int jh = 0; jh < 2; ++jh)
                #pragma unroll
                for (int ks = 0; ks < 2; ++ks)
                    bk[jh][ks] = *reinterpret_cast<const s16x8*>(
                        kb + (size_t)(j0 + 16 * jh + c) * DH + 32 * ks + 8 * g);
            #pragma unroll
            for (int rs = 0; rs < 2; ++rs)
                #pragma unroll
                for (int jh = 0; jh < 2; ++jh) {
                    f32x4 x = {0.f, 0.f, 0.f, 0.f};
                    x = MFMA(aq[rs][0], bk[jh][0], x);
                    x = MFMA(aq[rs][1], bk[jh][1], x);
                    SK[rs][jh] = x;
                }
        }
        // --- p = exp(s), l accumulation, global p write, P scratch ---
        #pragma unroll
        for (int rs = 0; rs < 2; ++rs)
            #pragma unroll
            for (int jh = 0; jh < 2; ++jh)
                #pragma unroll
                for (int r = 0; r < 4; ++r) {
                    const int il = 16 * rs + 4 * g + r;
                    const int jl = 16 * jh + c;
                    float s = (SK[rs][jh][r] + rel[rs][jh][r]) * 0.125f;
                    float p = (j0 + jl <= i0 + il) ? __expf(s) : 0.0f;
                    lsum[rs][r] += p;
                    ab[(size_t)(i0 + il) * L + j0 + jl] = p;
                    Pw[il][jl] = f2b(p);
                }
        // --- PV: O += P @ V  (V^T fragments straight from global) ---
        s16x8 pa[2];
        #pragma unroll
        for (int rs2 = 0; rs2 < 2; ++rs2)
            pa[rs2] = *reinterpret_cast<const s16x8*>(&Pw[16 * rs2 + c][8 * g]);
        #pragma unroll
        for (int cs = 0; cs < 4; ++cs) {
            s16x8 vtb = *reinterpret_cast<const s16x8*>(
                vt + (size_t)(16 * cs + c) * L + j0 + 8 * g);
            #pragma unroll
            for (int rs2 = 0; rs2 < 2; ++rs2)
                O[rs2][cs] = MFMA(pa[rs2], vtb, O[rs2][cs]);
        }
    }

    // --- merges (only barriers in the kernel) ---
    #pragma unroll
    for (int rs = 0; rs < 2; ++rs)
        #pragma unroll
        for (int r = 0; r < 4; ++r) {
            float s = lsum[rs][r];
            s += __shfl_xor(s, 1); s += __shfl_xor(s, 2);
            s += __shfl_xor(s, 4); s += __shfl_xor(s, 8);
            if (c == 0) lred[w][16 * rs + 4 * g + r] = s;
        }
    #pragma unroll
    for (int rs2 = 0; rs2 < 2; ++rs2)
        #pragma unroll
        for (int cs = 0; cs < 4; ++cs)
            #pragma unroll
            for (int r = 0; r < 4; ++r)
                Ored[w][16 * rs2 + 4 * g + r][16 * cs + c] = O[rs2][cs][r];
    __syncthreads();
    if (tid < 32) {
        float l = lred[0][tid] + lred[1][tid] + lred[2][tid] + lred[3][tid];
        float inv = 1.0f / l;
        linvs[tid] = inv;
        linvg[(size_t)bh * L + i0 + tid] = inv;
    }
    __syncthreads();
    {
        const int i = tid >> 3, d8 = (tid & 7) * 8;
        const float inv = linvs[i];
        ushort o[8];
        #pragma unroll
        for (int e = 0; e < 8; ++e) {
            float a = Ored[0][i][d8 + e] + Ored[1][i][d8 + e]
                    + Ored[2][i][d8 + e] + Ored[3][i][d8 + e];
            o[e] = f2b(a * inv);
        }
        *reinterpret_cast<uint4*>(
            &ows[((size_t)b * L + i0 + i) * DMODEL + h * DH + d8]) =
            *reinterpret_cast<const uint4*>(&o[0]);
    }
}

// ---------- in-place row rescale of attnw + masked-region zero fill ----------
__global__ __launch_bounds__(256)
void rescale(float* __restrict__ attnw, const float* __restrict__ linvg) {
    const int blk = blockIdx.x;
    const int bh = blk >> 11, i = blk & 2047;
    const float inv = linvg[(size_t)bh * L + i];
    float* rowp = attnw + ((size_t)bh * L + i) * L;
    const int c8 = threadIdx.x * 8;
    float4 a, b2;
    if (c8 <= i) {
        a  = *reinterpret_cast<const float4*>(rowp + c8);
        b2 = *reinterpret_cast<const float4*>(rowp + c8 + 4);
        a.x  = (c8 + 0 <= i) ? a.x  * inv : 0.f;
        a.y  = (c8 + 1 <= i) ? a.y  * inv : 0.f;
        a.z  = (c8 + 2 <= i) ? a.z  * inv : 0.f;
        a.w  = (c8 + 3 <= i) ? a.w  * inv : 0.f;
        b2.x = (c8 + 4 <= i) ? b2.x * inv : 0.f;
        b2.y = (c8 + 5 <= i) ? b2.y * inv : 0.f;
        b2.z = (c8 + 6 <= i) ? b2.z * inv : 0.f;
        b2.w = (c8 + 7 <= i) ? b2.w * inv : 0.f;
    } else {
        a = make_float4(0.f, 0.f, 0.f, 0.f);
        b2 = a;
    }
    *reinterpret_cast<float4*>(rowp + c8) = a;
    *reinterpret_cast<float4*>(rowp + c8 + 4) = b2;
}

extern "C" void kernel_launch(void* const* d_in, const int* in_sizes, int n_in,
                              void* d_out, int out_size, void* d_ws, size_t ws_size,
                              hipStream_t stream) {
    const float* q_in = (const float*)d_in[0];
    const float* k_in = (const float*)d_in[1];
    const float* v_in = (const float*)d_in[2];
    const float* Wq  = (const float*)d_in[4];
    const float* bq  = (const float*)d_in[5];
    const float* Wk  = (const float*)d_in[6];
    const float* bk  = (const float*)d_in[7];
    const float* Wv  = (const float*)d_in[8];
    const float* bv  = (const float*)d_in[9];
    const float* Wfc = (const float*)d_in[10];
    const float* bfc = (const float*)d_in[11];
    const float* E   = (const float*)d_in[12];

    float* out0  = (float*)d_out;                        // (B,L,D) f32
    float* attnw = out0 + (size_t)2 * L * DMODEL;        // (B,H,L,L) f32

    const size_t NA = (size_t)NROWS * DMODEL;            // 2,097,152
    ushort* ws = (ushort*)d_ws;
    ushort* Ebf  = ws;                                   // 131072
    ushort* Wqt  = Ebf + (size_t)L * DH;
    ushort* Wkt  = Wqt + 262144;
    ushort* Wvt  = Wkt + 262144;
    ushort* Wfct = Wvt + 262144;
    ushort* qws  = Wfct + 262144;
    ushort* kws  = qws + NA;
    ushort* vtg  = kws + NA;                             // (B,H,DH,L) bf16
    ushort* ows  = vtg + NA;
    float*  linvg = (float*)(ows + NA);                  // (B,H,L) f32

    cvt_bf16<<<dim3(64), 256, 0, stream>>>(E, Ebf, (int)(L * DH / 8));
    transpose_w<<<dim3(8, 8, 4), 256, 0, stream>>>(Wq, Wk, Wv, Wfc, Wqt, Wkt, Wvt, Wfct);
    gemm_bf16<<<dim3(8, 32, 2), 256, 0, stream>>>(q_in, k_in, Wqt, Wkt,
                                                  bq, bk, qws, kws, 1, 1);
    gemm_bf16<<<dim3(8, 32, 1), 256, 0, stream>>>(v_in, v_in, Wvt, Wvt,
                                                  bv, bv, vtg, vtg, 1, 2);
    attn<<<dim3(1024), 256, 0, stream>>>(qws, kws, vtg, Ebf, attnw, ows, linvg);
    rescale<<<dim3(32768), 256, 0, stream>>>(attnw, linvg);
    gemm_bf16<<<dim3(8, 32, 1), 256, 0, stream>>>(ows, ows, Wfct, Wfct,
                                                  bfc, bfc, out0, out0, 0, 0);
}